// Round 4
// baseline (206.107 us; speedup 1.0000x reference)
//
#include <hip/hip_runtime.h>
#include <hip/hip_cooperative_groups.h>

// PointPillarsScatter: out[b][c][y][x] = sum_{p: coords[p]=(b,_,y,x)} vf[p][c]
// B=4, C=64, NY=496, NX=432, P=48000. Output (B,C,NY,NX) f32 ~219 MB.
//
// Single cooperative kernel, 3 phases separated by grid.sync():
//   P1: head[cell] = -1  (grid-stride int4 fill, 3.4 MB)
//   P2: per-pillar linked list via atomicExch (head/nxt in d_ws)
//   P3: dense gather: block grid-strides over 256-cell tiles; heads staged in
//       double-buffered LDS (next tile prefetches under current tile's stores);
//       each thread: 4 cells x 16 channels, chain walked once, float4 vf loads,
//       16 coalesced 1KB/wave float4 stores. Only large traffic = 219 MB write.

#define CC 64
#define GNY 496
#define GNX 432
#define S_CELLS (GNY * GNX)         // 214272 (divisible by 256)
#define NUM_CELLS (4 * S_CELLS)     // 857088
#define NTILES (NUM_CELLS / 256)    // 3348
#define FUSED_BLOCKS 512            // 2 blocks/CU on 256 CUs -> co-resident

namespace cg = cooperative_groups;

__device__ __forceinline__ void gather_tile(int tile, int t, const int* hsrc,
                                            const float4* __restrict__ vf4,
                                            const int* __restrict__ nxt,
                                            float* __restrict__ out) {
    int lane = t & 63;
    int cgp = t >> 6;                      // channel group: channels cgp*16..+15
    int s0 = tile * 256 + lane * 4;        // 4 consecutive cells
    int b = s0 / S_CELLS;                  // tiles never straddle batches
    int r0 = s0 - b * S_CELLS;

    // 4 heads per thread from LDS (ds_read_b128)
    int4 h4 = ((const int4*)hsrc)[lane];
    int hh[4] = {h4.x, h4.y, h4.z, h4.w};

    float acc[4][16];
    #pragma unroll
    for (int cell = 0; cell < 4; ++cell)
        #pragma unroll
        for (int i = 0; i < 16; ++i)
            acc[cell][i] = 0.f;

    #pragma unroll
    for (int cell = 0; cell < 4; ++cell) {
        for (int p = hh[cell]; p >= 0; ) {
            int pn = nxt[p];
            int pb = p * 16 + cgp * 4;     // float4 index into vf
            #pragma unroll
            for (int j = 0; j < 4; ++j) {
                float4 v = vf4[pb + j];
                acc[cell][4 * j + 0] += v.x;
                acc[cell][4 * j + 1] += v.y;
                acc[cell][4 * j + 2] += v.z;
                acc[cell][4 * j + 3] += v.w;
            }
            p = pn;
        }
    }

    size_t outbase = (size_t)b * (CC * S_CELLS)
                   + (size_t)(cgp * 16) * S_CELLS + r0;
    #pragma unroll
    for (int i = 0; i < 16; ++i) {
        float4 o = make_float4(acc[0][i], acc[1][i], acc[2][i], acc[3][i]);
        *(float4*)&out[outbase + (size_t)i * S_CELLS] = o;
    }
}

__global__ __launch_bounds__(256, 2)
void pp_fused(const float4* __restrict__ vf4,
              const int* __restrict__ coords,
              int* __restrict__ head,
              int* __restrict__ nxt,
              float* __restrict__ out,
              int P) {
    cg::grid_group grid = cg::this_grid();
    int t = threadIdx.x;
    int gtid = blockIdx.x * 256 + t;
    int gsz = gridDim.x * 256;

    // ---- Phase 1: init head to -1 ----
    int4* head4 = (int4*)head;
    for (int i = gtid; i < NUM_CELLS / 4; i += gsz)
        head4[i] = make_int4(-1, -1, -1, -1);

    __threadfence();
    grid.sync();

    // ---- Phase 2: build per-cell linked lists ----
    const int4* c4 = (const int4*)coords;
    for (int p = gtid; p < P; p += gsz) {
        int4 c = c4[p];                           // (b, z, y, x)
        int s = (c.x * GNY + c.z) * GNX + c.w;
        nxt[p] = atomicExch(&head[s], p);
    }

    __threadfence();
    grid.sync();

    // ---- Phase 3: dense gather, double-buffered LDS head staging ----
    __shared__ alignas(16) int lds[2][256];
    int tile = blockIdx.x;
    if (tile < NTILES) lds[0][t] = head[tile * 256 + t];
    int buf = 0;
    for (; tile < NTILES; tile += gridDim.x) {
        __syncthreads();                          // lds[buf] ready
        int ntile = tile + gridDim.x;
        if (ntile < NTILES)                       // prefetch under stores
            lds[buf ^ 1][t] = head[ntile * 256 + t];
        gather_tile(tile, t, lds[buf], vf4, nxt, out);
        buf ^= 1;
    }
}

// ---------------- fallback: 3-kernel path (round-3 proven) ----------------
__global__ void pp_init_head(int4* __restrict__ head4, int n4) {
    int stride = gridDim.x * blockDim.x;
    for (int i = blockIdx.x * blockDim.x + threadIdx.x; i < n4; i += stride)
        head4[i] = make_int4(-1, -1, -1, -1);
}

__global__ void pp_build(const int* __restrict__ coords,
                         int* __restrict__ head,
                         int* __restrict__ nxt,
                         int P) {
    int p = blockIdx.x * blockDim.x + threadIdx.x;
    if (p >= P) return;
    int4 c = ((const int4*)coords)[p];
    int s = (c.x * GNY + c.z) * GNX + c.w;
    nxt[p] = atomicExch(&head[s], p);
}

__global__ __launch_bounds__(256) void pp_gather(const float4* __restrict__ vf4,
                                                 const int* __restrict__ head,
                                                 const int* __restrict__ nxt,
                                                 float* __restrict__ out) {
    __shared__ alignas(16) int lds[256];
    int t = threadIdx.x;
    lds[t] = head[blockIdx.x * 256 + t];
    __syncthreads();
    gather_tile(blockIdx.x, t, lds, vf4, nxt, out);
}

extern "C" void kernel_launch(void* const* d_in, const int* in_sizes, int n_in,
                              void* d_out, int out_size, void* d_ws, size_t ws_size,
                              hipStream_t stream) {
    const float* vf     = (const float*)d_in[0];
    const int*   coords = (const int*)d_in[1];
    float*       out    = (float*)d_out;

    int P = in_sizes[1] / 4;                      // 48000

    size_t need = (size_t)(NUM_CELLS + P) * sizeof(int);
    if (ws_size < need) return;                   // cannot happen per harness sizing

    int* head = (int*)d_ws;
    int* nxt  = head + NUM_CELLS;

    int dev = 0, coop = 0;
    hipGetDevice(&dev);
    hipDeviceGetAttribute(&coop, hipDeviceAttributeCooperativeLaunch, dev);

    if (coop) {
        const float4* vf4 = (const float4*)vf;
        void* args[] = {(void*)&vf4, (void*)&coords, (void*)&head,
                        (void*)&nxt, (void*)&out, (void*)&P};
        hipError_t e = hipLaunchCooperativeKernel((const void*)pp_fused,
                                                  dim3(FUSED_BLOCKS), dim3(256),
                                                  args, 0, stream);
        if (e == hipSuccess) return;
    }

    // fallback: 3 separate kernels
    pp_init_head<<<512, 256, 0, stream>>>((int4*)head, NUM_CELLS / 4);
    pp_build<<<(P + 255) / 256, 256, 0, stream>>>(coords, head, nxt, P);
    pp_gather<<<NTILES, 256, 0, stream>>>((const float4*)vf, head, nxt, out);
}

// Round 5
// 47.278 us; speedup vs baseline: 4.3595x; 4.3595x over previous
//
#include <hip/hip_runtime.h>
#include <hip/hip_cooperative_groups.h>

// PointPillarsScatter: out[b][c][y][x] = sum_{p: coords[p]=(b,_,y,x)} vf[p][c]
// B=4, C=64, NY=496, NX=432, P=48000. Output (B,C,NY,NX) f32 ~219 MB.
//
// Single cooperative kernel, 3 phases separated by grid.sync():
//   P1: head[cell] = -1  (grid-stride int4 fill, 3.4 MB in d_ws)
//   P2: per-pillar linked list via atomicExch (head/nxt in d_ws)
//   P3: dense gather, grid-stride over 256-cell tiles, heads staged in LDS;
//       each thread: 4 cells x 16 channels, chain walked once, float4 vf
//       loads, 16 coalesced 1KB/wave float4 stores.
// R4 lesson: grid MUST be sized from the occupancy query, not a conservative
// constant — 512 blocks (8 waves/CU) ran the store phase at 1 TB/s (TLP-
// limited). Target 8 blocks/CU -> 2048 blocks -> 32 waves/CU.

#define CC 64
#define GNY 496
#define GNX 432
#define S_CELLS (GNY * GNX)         // 214272 (divisible by 256)
#define NUM_CELLS (4 * S_CELLS)     // 857088
#define NTILES (NUM_CELLS / 256)    // 3348

namespace cg = cooperative_groups;

__device__ __forceinline__ void gather_tile(int tile, int t, const int* hsrc,
                                            const float4* __restrict__ vf4,
                                            const int* __restrict__ nxt,
                                            float* __restrict__ out) {
    int lane = t & 63;
    int cgp = t >> 6;                      // channel group: channels cgp*16..+15
    int s0 = tile * 256 + lane * 4;        // 4 consecutive cells
    int b = s0 / S_CELLS;                  // tiles never straddle batches
    int r0 = s0 - b * S_CELLS;

    int4 h4 = ((const int4*)hsrc)[lane];   // ds_read_b128
    int hh[4] = {h4.x, h4.y, h4.z, h4.w};

    float acc[4][16];
    #pragma unroll
    for (int cell = 0; cell < 4; ++cell)
        #pragma unroll
        for (int i = 0; i < 16; ++i)
            acc[cell][i] = 0.f;

    #pragma unroll
    for (int cell = 0; cell < 4; ++cell) {
        for (int p = hh[cell]; p >= 0; ) {
            int pn = nxt[p];
            int pb = p * 16 + cgp * 4;     // float4 index into vf
            #pragma unroll
            for (int j = 0; j < 4; ++j) {
                float4 v = vf4[pb + j];
                acc[cell][4 * j + 0] += v.x;
                acc[cell][4 * j + 1] += v.y;
                acc[cell][4 * j + 2] += v.z;
                acc[cell][4 * j + 3] += v.w;
            }
            p = pn;
        }
    }

    size_t outbase = (size_t)b * (CC * S_CELLS)
                   + (size_t)(cgp * 16) * S_CELLS + r0;
    #pragma unroll
    for (int i = 0; i < 16; ++i) {
        float4 o = make_float4(acc[0][i], acc[1][i], acc[2][i], acc[3][i]);
        *(float4*)&out[outbase + (size_t)i * S_CELLS] = o;
    }
}

__global__ __launch_bounds__(256, 4)
void pp_fused(const float4* __restrict__ vf4,
              const int* __restrict__ coords,
              int* __restrict__ head,
              int* __restrict__ nxt,
              float* __restrict__ out,
              int P) {
    cg::grid_group grid = cg::this_grid();
    int t = threadIdx.x;
    int gtid = blockIdx.x * 256 + t;
    int gsz = gridDim.x * 256;

    // ---- Phase 1: init head to -1 ----
    int4* head4 = (int4*)head;
    for (int i = gtid; i < NUM_CELLS / 4; i += gsz)
        head4[i] = make_int4(-1, -1, -1, -1);

    __threadfence();
    grid.sync();

    // ---- Phase 2: build per-cell linked lists ----
    const int4* c4 = (const int4*)coords;
    for (int p = gtid; p < P; p += gsz) {
        int4 c = c4[p];                           // (b, z, y, x)
        int s = (c.x * GNY + c.z) * GNX + c.w;
        nxt[p] = atomicExch(&head[s], p);
    }

    __threadfence();
    grid.sync();

    // ---- Phase 3: dense gather, LDS head staging, grid-stride tiles ----
    __shared__ alignas(16) int lds[256];
    for (int tile = blockIdx.x; tile < NTILES; tile += gridDim.x) {
        lds[t] = head[tile * 256 + t];
        __syncthreads();
        gather_tile(tile, t, lds, vf4, nxt, out);
        __syncthreads();
    }
}

// ---------------- fallback: 3-kernel path (round-3 proven, 47 us) ----------
__global__ void pp_init_head(int4* __restrict__ head4, int n4) {
    int stride = gridDim.x * blockDim.x;
    for (int i = blockIdx.x * blockDim.x + threadIdx.x; i < n4; i += stride)
        head4[i] = make_int4(-1, -1, -1, -1);
}

__global__ void pp_build(const int* __restrict__ coords,
                         int* __restrict__ head,
                         int* __restrict__ nxt,
                         int P) {
    int p = blockIdx.x * blockDim.x + threadIdx.x;
    if (p >= P) return;
    int4 c = ((const int4*)coords)[p];
    int s = (c.x * GNY + c.z) * GNX + c.w;
    nxt[p] = atomicExch(&head[s], p);
}

__global__ __launch_bounds__(256) void pp_gather(const float4* __restrict__ vf4,
                                                 const int* __restrict__ head,
                                                 const int* __restrict__ nxt,
                                                 float* __restrict__ out) {
    __shared__ alignas(16) int lds[256];
    int t = threadIdx.x;
    lds[t] = head[blockIdx.x * 256 + t];
    __syncthreads();
    gather_tile(blockIdx.x, t, lds, vf4, nxt, out);
}

extern "C" void kernel_launch(void* const* d_in, const int* in_sizes, int n_in,
                              void* d_out, int out_size, void* d_ws, size_t ws_size,
                              hipStream_t stream) {
    const float* vf     = (const float*)d_in[0];
    const int*   coords = (const int*)d_in[1];
    float*       out    = (float*)d_out;

    int P = in_sizes[1] / 4;                      // 48000

    size_t need = (size_t)(NUM_CELLS + P) * sizeof(int);
    if (ws_size < need) return;                   // cannot happen per harness sizing

    int* head = (int*)d_ws;
    int* nxt  = head + NUM_CELLS;

    // Size the cooperative grid from the ACTUAL occupancy limit (R4 lesson).
    int dev = 0, coop = 0, numCU = 0, maxBlocksPerCU = 0;
    hipGetDevice(&dev);
    hipDeviceGetAttribute(&coop, hipDeviceAttributeCooperativeLaunch, dev);
    hipDeviceGetAttribute(&numCU, hipDeviceAttributeMultiprocessorCount, dev);
    hipOccupancyMaxActiveBlocksPerMultiprocessor(&maxBlocksPerCU,
                                                 (const void*)pp_fused, 256, 0);
    int blocks = maxBlocksPerCU * numCU;
    if (blocks > NTILES) blocks = NTILES;

    if (coop && maxBlocksPerCU >= 4) {
        const float4* vf4 = (const float4*)vf;
        void* args[] = {(void*)&vf4, (void*)&coords, (void*)&head,
                        (void*)&nxt, (void*)&out, (void*)&P};
        hipError_t e = hipLaunchCooperativeKernel((const void*)pp_fused,
                                                  dim3(blocks), dim3(256),
                                                  args, 0, stream);
        if (e == hipSuccess) return;
    }

    // fallback: 3 separate kernels
    pp_init_head<<<512, 256, 0, stream>>>((int4*)head, NUM_CELLS / 4);
    pp_build<<<(P + 255) / 256, 256, 0, stream>>>(coords, head, nxt, P);
    pp_gather<<<NTILES, 256, 0, stream>>>((const float4*)vf, head, nxt, out);
}